// Round 1
// baseline (551.648 us; speedup 1.0000x reference)
//
#include <hip/hip_runtime.h>

typedef unsigned short u16;
typedef unsigned int u32;
typedef __bf16 bf16x8 __attribute__((ext_vector_type(8)));
typedef float floatx4 __attribute__((ext_vector_type(4)));

// Problem constants: B=4, S=1024, DIM=2048, HQ=16, HKV=4, HD=128, G=4
__device__ __forceinline__ u16 f2bf(float x) {
  union { float f; u32 u; } v; v.f = x;
  u32 r = v.u + 0x7fffu + ((v.u >> 16) & 1u);   // RNE
  return (u16)(r >> 16);
}
__device__ __forceinline__ float bf2f(u16 x) {
  union { float f; u32 u; } v; v.u = ((u32)x) << 16;
  return v.f;
}

// ---------------- f32 -> bf16 conversion, 4 elems/thread ----------------
__global__ __launch_bounds__(256) void cvt_f32_bf16(const float* __restrict__ s,
                                                    u16* __restrict__ d, int n4) {
  int i = blockIdx.x * 256 + threadIdx.x;
  if (i >= n4) return;
  float4 v = ((const float4*)s)[i];
  uint2 o;
  o.x = (u32)f2bf(v.x) | ((u32)f2bf(v.y) << 16);
  o.y = (u32)f2bf(v.z) | ((u32)f2bf(v.w) << 16);
  ((uint2*)d)[i] = o;
}

// ---------------- RoPE in-place on [B,S,H,128] bf16 ----------------
// one thread per (b,s,h,pair); pair p rotates elements (2p, 2p+1) by freqs[s][p]
__global__ __launch_bounds__(256) void rope_kernel(u16* __restrict__ t,
                                                   const float* __restrict__ fr,
                                                   int lgH, int total) {
  int idx = blockIdx.x * 256 + threadIdx.x;
  if (idx >= total) return;
  int p = idx & 63;
  int bsh = idx >> 6;              // (b*1024+s)*H + h
  int s = (bsh >> lgH) & 1023;
  float th = fr[s * 64 + p];
  float sn, cs;
  sincosf(th, &sn, &cs);
  u32* base = (u32*)(t + (size_t)bsh * 128 + p * 2);
  u32 pr = *base;
  float e = bf2f((u16)(pr & 0xffffu));
  float o = bf2f((u16)(pr >> 16));
  u16 re = f2bf(e * cs - o * sn);
  u16 im = f2bf(e * sn + o * cs);
  *base = (u32)re | ((u32)im << 16);
}

// ---------------- C = A (M,K) * B^T, B given as (N,K); all bf16 in, f32 acc ----
// EPI 0: f32 store to Cf (M,N). EPI 1: bf16 store to Cb (M,N).
// EPI 2: bf16 transposed store for V: Cb layout [b][kv][hd][s]  (M=b*1024+s, N=kv*128+hd)
template <int EPI>
__global__ __launch_bounds__(256, 2) void gemm_bt(const u16* __restrict__ A,
                                                  const u16* __restrict__ Bw,
                                                  float* __restrict__ Cf,
                                                  u16* __restrict__ Cb,
                                                  int M, int N, int K) {
  __shared__ __align__(16) u16 sA[128 * 64];
  __shared__ __align__(16) u16 sB[128 * 64];
  const int tid = threadIdx.x;
  const int wave = tid >> 6, lane = tid & 63;
  const int quad = lane >> 4, l16 = lane & 15;
  const int m0 = blockIdx.x * 128, n0 = blockIdx.y * 128;
  const int wm = (wave >> 1) * 64, wn = (wave & 1) * 64;
  floatx4 acc[4][4] = {};
  for (int k0 = 0; k0 < K; k0 += 64) {
    __syncthreads();
    #pragma unroll
    for (int c = tid; c < 1024; c += 256) {
      int row = c >> 3, col8 = c & 7;
      *(int4*)&sA[row * 64 + col8 * 8] =
          *(const int4*)(A + (size_t)(m0 + row) * K + k0 + col8 * 8);
      *(int4*)&sB[row * 64 + col8 * 8] =
          *(const int4*)(Bw + (size_t)(n0 + row) * K + k0 + col8 * 8);
    }
    __syncthreads();
    #pragma unroll
    for (int ks = 0; ks < 64; ks += 32) {
      bf16x8 af[4], bw[4];
      #pragma unroll
      for (int i = 0; i < 4; i++)
        af[i] = *(const bf16x8*)&sA[(wm + i * 16 + l16) * 64 + ks + quad * 8];
      #pragma unroll
      for (int j = 0; j < 4; j++)
        bw[j] = *(const bf16x8*)&sB[(wn + j * 16 + l16) * 64 + ks + quad * 8];
      #pragma unroll
      for (int i = 0; i < 4; i++)
        #pragma unroll
        for (int j = 0; j < 4; j++)
          acc[i][j] = __builtin_amdgcn_mfma_f32_16x16x32_bf16(af[i], bw[j], acc[i][j], 0, 0, 0);
    }
  }
  // epilogue: C/D layout col=lane&15, row=quad*4+reg
  #pragma unroll
  for (int i = 0; i < 4; i++) {
    #pragma unroll
    for (int j = 0; j < 4; j++) {
      const int row0 = m0 + wm + i * 16 + quad * 4;
      const int col = n0 + wn + j * 16 + l16;
      #pragma unroll
      for (int r = 0; r < 4; r++) {
        int m = row0 + r;
        if (EPI == 0) {
          Cf[(size_t)m * N + col] = acc[i][j][r];
        } else if (EPI == 1) {
          Cb[(size_t)m * N + col] = f2bf(acc[i][j][r]);
        } else {
          int b = m >> 10, sI = m & 1023, kvh = col >> 7, hd = col & 127;
          Cb[((size_t)((b * 4 + kvh) * 128 + hd)) * 1024 + sI] = f2bf(acc[i][j][r]);
        }
      }
    }
  }
}

// ---------------- causal flash attention ----------------
// q: [B,S,HQ,128] bf16 (rope'd), k: [B,S,HKV,128] bf16 (rope'd), vt: [B,HKV,128,S] bf16
// o: [B,S,HQ,128] bf16.  grid = (S/128, B*HQ), 256 threads (4 waves, 32 q-rows each)
__global__ __launch_bounds__(256, 2) void flash_attn(const u16* __restrict__ q,
                                                     const u16* __restrict__ k,
                                                     const u16* __restrict__ vt,
                                                     u16* __restrict__ o) {
  const int qt = blockIdx.x;
  const int head = blockIdx.y;
  const int b = head >> 4, hq = head & 15, kv = hq >> 2;
  const int tid = threadIdx.x;
  const int wave = tid >> 6, lane = tid & 63;
  const int quad = lane >> 4, l16 = lane & 15;
  __shared__ __align__(16) u16 sQ[128 * 128];   // [qrow][hd]
  __shared__ __align__(16) u16 sKP[64 * 128];   // K tile [key][hd]; reused as P [qrow][key]
  __shared__ __align__(16) u16 sV[128 * 64];    // V^T tile [hd][key]
  const u16* qbase = q + ((size_t)(b * 1024 + qt * 128) * 16 + hq) * 128;
  #pragma unroll
  for (int c = tid; c < 2048; c += 256) {
    int row = c >> 4, col8 = c & 15;
    *(int4*)&sQ[row * 128 + col8 * 8] = *(const int4*)(qbase + (size_t)row * 2048 + col8 * 8);
  }
  const floatx4 vzero = {0.f, 0.f, 0.f, 0.f};
  floatx4 o_acc[2][8];
  float mrow[2][4], lrow[2][4];
  #pragma unroll
  for (int i = 0; i < 2; i++) {
    #pragma unroll
    for (int j = 0; j < 8; j++) o_acc[i][j] = vzero;
    #pragma unroll
    for (int r = 0; r < 4; r++) { mrow[i][r] = -1e30f; lrow[i][r] = 0.f; }
  }
  const float scale = 0.08838834764831845f;  // 1/sqrt(128)
  const int ktmax = 2 * qt + 1;
  for (int kt = 0; kt <= ktmax; kt++) {
    const int t0 = kt * 64;
    __syncthreads();  // previous iteration's LDS reads complete
    {
      const u16* kbase = k + ((size_t)(b * 1024 + t0) * 4 + kv) * 128;
      #pragma unroll
      for (int c = tid; c < 1024; c += 256) {
        int row = c >> 4, col8 = c & 15;
        *(int4*)&sKP[row * 128 + col8 * 8] = *(const int4*)(kbase + (size_t)row * 512 + col8 * 8);
      }
      const u16* vbase = vt + (size_t)(b * 4 + kv) * 131072 + t0;
      #pragma unroll
      for (int c = tid; c < 1024; c += 256) {
        int row = c >> 3, col8 = c & 7;
        *(int4*)&sV[row * 64 + col8 * 8] = *(const int4*)(vbase + (size_t)row * 1024 + col8 * 8);
      }
    }
    __syncthreads();
    // S = Q K^T  (rows wave*32..+31, keys t0..t0+63)
    floatx4 s_acc[2][4];
    #pragma unroll
    for (int i = 0; i < 2; i++)
      #pragma unroll
      for (int j = 0; j < 4; j++) s_acc[i][j] = vzero;
    #pragma unroll
    for (int ks = 0; ks < 128; ks += 32) {
      bf16x8 aq[2], bk[4];
      #pragma unroll
      for (int i = 0; i < 2; i++)
        aq[i] = *(const bf16x8*)&sQ[(wave * 32 + i * 16 + l16) * 128 + ks + quad * 8];
      #pragma unroll
      for (int j = 0; j < 4; j++)
        bk[j] = *(const bf16x8*)&sKP[(j * 16 + l16) * 128 + ks + quad * 8];
      #pragma unroll
      for (int i = 0; i < 2; i++)
        #pragma unroll
        for (int j = 0; j < 4; j++)
          s_acc[i][j] = __builtin_amdgcn_mfma_f32_16x16x32_bf16(aq[i], bk[j], s_acc[i][j], 0, 0, 0);
    }
    __syncthreads();  // everyone done reading K before P overwrites sKP
    // online softmax (each row lives in the 16 lanes of one quad)
    #pragma unroll
    for (int i = 0; i < 2; i++) {
      #pragma unroll
      for (int r = 0; r < 4; r++) {
        const int row_l = wave * 32 + i * 16 + quad * 4 + r;
        const int sg = qt * 128 + row_l;
        float mx = -1e30f;
        #pragma unroll
        for (int j = 0; j < 4; j++) {
          float v = s_acc[i][j][r] * scale;
          if (t0 + j * 16 + l16 > sg) v = -1e30f;  // causal mask
          s_acc[i][j][r] = v;
          mx = fmaxf(mx, v);
        }
        #pragma unroll
        for (int d = 1; d < 16; d <<= 1) mx = fmaxf(mx, __shfl_xor(mx, d));
        float mold = mrow[i][r];
        float mnew = fmaxf(mold, mx);
        float alpha = __expf(mold - mnew);
        mrow[i][r] = mnew;
        float rs = 0.f;
        #pragma unroll
        for (int j = 0; j < 4; j++) {
          float p = __expf(s_acc[i][j][r] - mnew);
          s_acc[i][j][r] = p;
          rs += p;
        }
        #pragma unroll
        for (int d = 1; d < 16; d <<= 1) rs += __shfl_xor(rs, d);
        lrow[i][r] = lrow[i][r] * alpha + rs;
        #pragma unroll
        for (int j = 0; j < 8; j++) o_acc[i][j][r] *= alpha;
      }
    }
    // write P (bf16) into sKP as [qrow][key]; wave-private rows, no barrier needed
    #pragma unroll
    for (int i = 0; i < 2; i++)
      #pragma unroll
      for (int j = 0; j < 4; j++)
        #pragma unroll
        for (int r = 0; r < 4; r++)
          sKP[(wave * 32 + i * 16 + quad * 4 + r) * 64 + j * 16 + l16] = f2bf(s_acc[i][j][r]);
    // O += P * V  (A = P rows k-contiguous, B = V^T rows k-contiguous)
    #pragma unroll
    for (int ks = 0; ks < 64; ks += 32) {
      bf16x8 ap[2], bv[8];
      #pragma unroll
      for (int i = 0; i < 2; i++)
        ap[i] = *(const bf16x8*)&sKP[(wave * 32 + i * 16 + l16) * 64 + ks + quad * 8];
      #pragma unroll
      for (int j = 0; j < 8; j++)
        bv[j] = *(const bf16x8*)&sV[(j * 16 + l16) * 64 + ks + quad * 8];
      #pragma unroll
      for (int i = 0; i < 2; i++)
        #pragma unroll
        for (int j = 0; j < 8; j++)
          o_acc[i][j] = __builtin_amdgcn_mfma_f32_16x16x32_bf16(ap[i], bv[j], o_acc[i][j], 0, 0, 0);
    }
  }
  // epilogue: O / l  -> bf16
  u16* obase = o + ((size_t)(b * 1024 + qt * 128) * 16 + hq) * 128;
  #pragma unroll
  for (int i = 0; i < 2; i++) {
    #pragma unroll
    for (int r = 0; r < 4; r++) {
      const int row_l = wave * 32 + i * 16 + quad * 4 + r;
      const float inv = 1.f / lrow[i][r];
      #pragma unroll
      for (int j = 0; j < 8; j++)
        obase[(size_t)row_l * 2048 + j * 16 + l16] = f2bf(o_acc[i][j][r] * inv);
    }
  }
}

extern "C" void kernel_launch(void* const* d_in, const int* in_sizes, int n_in,
                              void* d_out, int out_size, void* d_ws, size_t ws_size,
                              hipStream_t stream) {
  const float* x  = (const float*)d_in[0];
  // d_in[1] = start_pos (0, unused; causal mask applied directly)
  const float* fr = (const float*)d_in[2];
  // d_in[3] = mask (implemented as causal condition)
  const float* wq = (const float*)d_in[4];
  const float* wk = (const float*)d_in[5];
  const float* wv = (const float*)d_in[6];
  const float* wo = (const float*)d_in[7];
  float* out = (float*)d_out;

  char* ws = (char*)d_ws;
  // workspace layout (bytes): total ~79.7 MB
  u16* xb  = (u16*)(ws + 0);           // 4096x2048        16.78 MB
  u16* wqb = (u16*)(ws + 16777216);    // 2048x2048         8.39 MB
  u16* wkb = (u16*)(ws + 25165824);    //  512x2048         2.10 MB
  u16* wvb = (u16*)(ws + 27262976);    //  512x2048         2.10 MB
  u16* wob = (u16*)(ws + 29360128);    // 2048x2048         8.39 MB
  u16* qb  = (u16*)(ws + 37748736);    // [B,S,16,128]     16.78 MB
  u16* kb  = (u16*)(ws + 54525952);    // [B,S,4,128]       4.19 MB
  u16* vtb = (u16*)(ws + 58720256);    // [B,4,128,S]       4.19 MB
  u16* ob  = (u16*)(ws + 62914560);    // [B,S,16,128]     16.78 MB

  // 1) bf16 conversions
  cvt_f32_bf16<<<8192, 256, 0, stream>>>(x,  xb,  2097152);
  cvt_f32_bf16<<<4096, 256, 0, stream>>>(wq, wqb, 1048576);
  cvt_f32_bf16<<<1024, 256, 0, stream>>>(wk, wkb, 262144);
  cvt_f32_bf16<<<1024, 256, 0, stream>>>(wv, wvb, 262144);
  cvt_f32_bf16<<<4096, 256, 0, stream>>>(wo, wob, 1048576);

  // 2) projections (x @ w^T)
  gemm_bt<1><<<dim3(32, 16), 256, 0, stream>>>(xb, wqb, nullptr, qb, 4096, 2048, 2048);
  gemm_bt<1><<<dim3(32, 4),  256, 0, stream>>>(xb, wkb, nullptr, kb, 4096, 512, 2048);
  gemm_bt<2><<<dim3(32, 4),  256, 0, stream>>>(xb, wvb, nullptr, vtb, 4096, 512, 2048);

  // 3) RoPE on q and k
  rope_kernel<<<16384, 256, 0, stream>>>(qb, fr, 4, 4194304);
  rope_kernel<<<4096,  256, 0, stream>>>(kb, fr, 2, 1048576);

  // 4) causal flash attention
  flash_attn<<<dim3(8, 64), 256, 0, stream>>>(qb, kb, vtb, ob);

  // 5) output projection -> f32
  gemm_bt<0><<<dim3(32, 16), 256, 0, stream>>>(ob, wob, out, nullptr, 4096, 2048, 2048);
}

// Round 2
// 328.641 us; speedup vs baseline: 1.6786x; 1.6786x over previous
//
#include <hip/hip_runtime.h>

typedef unsigned short u16;
typedef unsigned int u32;
typedef __bf16 bf16x8 __attribute__((ext_vector_type(8)));
typedef float floatx4 __attribute__((ext_vector_type(4)));

// B=4, S=1024, DIM=2048, HQ=16, HKV=4, HD=128, G=4
__device__ __forceinline__ u16 f2bf(float x) {
  union { float f; u32 u; } v; v.f = x;
  u32 r = v.u + 0x7fffu + ((v.u >> 16) & 1u);   // RNE
  return (u16)(r >> 16);
}
__device__ __forceinline__ float bf2f(u16 x) {
  union { float f; u32 u; } v; v.u = ((u32)x) << 16;
  return v.f;
}

// async global->LDS, 16B per lane. LDS dest must be wave-uniform base + lane*16.
__device__ __forceinline__ void gl_lds16(const u16* g, u16* l) {
  __builtin_amdgcn_global_load_lds((const __attribute__((address_space(1))) void*)g,
                                   (__attribute__((address_space(3))) void*)l, 16, 0, 0);
}

// ---------------- fused f32 -> bf16 conversion of all 5 tensors ----------------
__global__ __launch_bounds__(256) void cvt_all(const float* __restrict__ x,
                                               const float* __restrict__ wq,
                                               const float* __restrict__ wk,
                                               const float* __restrict__ wv,
                                               const float* __restrict__ wo,
                                               u16* __restrict__ xb, u16* __restrict__ wqb,
                                               u16* __restrict__ wkb, u16* __restrict__ wvb,
                                               u16* __restrict__ wob) {
  int i = blockIdx.x * 256 + threadIdx.x;  // float4 index
  const float* s; u16* d; int off;
  if (i < 2097152)      { s = x;  d = xb;  off = 0; }
  else if (i < 3145728) { s = wq; d = wqb; off = 2097152; }
  else if (i < 3407872) { s = wk; d = wkb; off = 3145728; }
  else if (i < 3670016) { s = wv; d = wvb; off = 3407872; }
  else                  { s = wo; d = wob; off = 3670016; }
  i -= off;
  float4 v = ((const float4*)s)[i];
  uint2 o;
  o.x = (u32)f2bf(v.x) | ((u32)f2bf(v.y) << 16);
  o.y = (u32)f2bf(v.z) | ((u32)f2bf(v.w) << 16);
  ((uint2*)d)[i] = o;
}

// ---------------- RoPE in-place on [B,S,H,128] bf16; optional pre-scale --------
__global__ __launch_bounds__(256) void rope_kernel(u16* __restrict__ t,
                                                   const float* __restrict__ fr,
                                                   int lgH, int total, float scale) {
  int idx = blockIdx.x * 256 + threadIdx.x;
  if (idx >= total) return;
  int p = idx & 63;
  int bsh = idx >> 6;
  int s = (bsh >> lgH) & 1023;
  float th = fr[s * 64 + p];
  float sn, cs;
  sincosf(th, &sn, &cs);
  u32* base = (u32*)(t + (size_t)bsh * 128 + p * 2);
  u32 pr = *base;
  float e = bf2f((u16)(pr & 0xffffu));
  float o = bf2f((u16)(pr >> 16));
  u16 re = f2bf((e * cs - o * sn) * scale);
  u16 im = f2bf((e * sn + o * cs) * scale);
  *base = (u32)re | ((u32)im << 16);
}

// ---------------- shared GEMM core: 128x128 tile, K=2048, BK=64, async staging --
__device__ __forceinline__ void gemm_core(const u16* __restrict__ A, const u16* __restrict__ Bw,
                                          u16* sA, u16* sB, int m0, int n0,
                                          floatx4 acc[4][4]) {
  const int tid = threadIdx.x;
  const int wave = tid >> 6, lane = tid & 63;
  const int quad = lane >> 4, l16 = lane & 15;
  const int wm = (wave >> 1) * 64, wn = (wave & 1) * 64;
  const int srow = wave * 8 + (lane >> 3);       // staging row within 32-row chunk
  const int scol = (lane & 7) * 8;               // staging col (u16 elements)
  const int lds_off = wave * 512 + lane * 8;     // u16 elements: wave*1024B + lane*16B
  for (int k0 = 0; k0 < 2048; k0 += 64) {
    __syncthreads();
    #pragma unroll
    for (int c = 0; c < 4; c++) {
      gl_lds16(A + (size_t)(m0 + c * 32 + srow) * 2048 + k0 + scol, sA + c * 2048 + lds_off);
      gl_lds16(Bw + (size_t)(n0 + c * 32 + srow) * 2048 + k0 + scol, sB + c * 2048 + lds_off);
    }
    __syncthreads();
    #pragma unroll
    for (int ks = 0; ks < 64; ks += 32) {
      bf16x8 af[4], bw[4];
      #pragma unroll
      for (int i = 0; i < 4; i++)
        af[i] = *(const bf16x8*)&sA[(wm + i * 16 + l16) * 64 + ks + quad * 8];
      #pragma unroll
      for (int j = 0; j < 4; j++)
        bw[j] = *(const bf16x8*)&sB[(wn + j * 16 + l16) * 64 + ks + quad * 8];
      #pragma unroll
      for (int i = 0; i < 4; i++)
        #pragma unroll
        for (int j = 0; j < 4; j++)
          acc[i][j] = __builtin_amdgcn_mfma_f32_16x16x32_bf16(af[i], bw[j], acc[i][j], 0, 0, 0);
    }
  }
}

// ---------------- fused QKV projection GEMM ----------------
// grid (32, 24): by<16 -> Q (N=2048), by 16..19 -> K (N=512), by 20..23 -> V transposed
__global__ __launch_bounds__(256, 2) void gemm_qkv(const u16* __restrict__ xb,
                                                   const u16* __restrict__ wqb,
                                                   const u16* __restrict__ wkb,
                                                   const u16* __restrict__ wvb,
                                                   u16* __restrict__ qb, u16* __restrict__ kb,
                                                   u16* __restrict__ vtb) {
  __shared__ __align__(16) u16 sA[128 * 64];
  __shared__ __align__(16) u16 sB[128 * 64];
  const int by = blockIdx.y;
  const u16* Bw; int n0, mode;
  if (by < 16)      { Bw = wqb; n0 = by * 128;        mode = 0; }
  else if (by < 20) { Bw = wkb; n0 = (by - 16) * 128; mode = 1; }
  else              { Bw = wvb; n0 = (by - 20) * 128; mode = 2; }
  const int m0 = blockIdx.x * 128;
  floatx4 acc[4][4] = {};
  gemm_core(xb, Bw, sA, sB, m0, n0, acc);
  const int tid = threadIdx.x;
  const int wave = tid >> 6, lane = tid & 63;
  const int quad = lane >> 4, l16 = lane & 15;
  const int wm = (wave >> 1) * 64, wn = (wave & 1) * 64;
  #pragma unroll
  for (int i = 0; i < 4; i++) {
    #pragma unroll
    for (int j = 0; j < 4; j++) {
      const int row0 = m0 + wm + i * 16 + quad * 4;
      const int col = n0 + wn + j * 16 + l16;
      #pragma unroll
      for (int r = 0; r < 4; r++) {
        int m = row0 + r;
        u16 val = f2bf(acc[i][j][r]);
        if (mode == 0) {
          qb[(size_t)m * 2048 + col] = val;
        } else if (mode == 1) {
          kb[(size_t)m * 512 + col] = val;
        } else {
          int b = m >> 10, sI = m & 1023, kvh = col >> 7, hd = col & 127;
          vtb[((size_t)((b * 4 + kvh) * 128 + hd)) * 1024 + sI] = val;
        }
      }
    }
  }
}

// ---------------- output projection GEMM (fp32 out) ----------------
__global__ __launch_bounds__(256, 2) void gemm_out(const u16* __restrict__ ob,
                                                   const u16* __restrict__ wob,
                                                   float* __restrict__ Cf) {
  __shared__ __align__(16) u16 sA[128 * 64];
  __shared__ __align__(16) u16 sB[128 * 64];
  const int m0 = blockIdx.x * 128, n0 = blockIdx.y * 128;
  floatx4 acc[4][4] = {};
  gemm_core(ob, wob, sA, sB, m0, n0, acc);
  const int tid = threadIdx.x;
  const int wave = tid >> 6, lane = tid & 63;
  const int quad = lane >> 4, l16 = lane & 15;
  const int wm = (wave >> 1) * 64, wn = (wave & 1) * 64;
  #pragma unroll
  for (int i = 0; i < 4; i++) {
    #pragma unroll
    for (int j = 0; j < 4; j++) {
      const int row0 = m0 + wm + i * 16 + quad * 4;
      const int col = n0 + wn + j * 16 + l16;
      #pragma unroll
      for (int r = 0; r < 4; r++)
        Cf[(size_t)(row0 + r) * 2048 + col] = acc[i][j][r];
    }
  }
}

// ---------------- wave-autonomous causal flash attention ----------------
// q: [B,S,16,128] bf16 (rope'd, pre-scaled), k: [B,S,4,128] bf16 (rope'd),
// vt: [B,4,128,S] bf16, o: [B,S,16,128] bf16.
// 512 blocks x 4 waves; each wave owns 32 q-rows of one head; no __syncthreads.
// Block bi: chunk p = 31 - (bi>>4) (longest first), head = (bi&15)*4 + wave
// (4 waves of a block share the same kv head -> shared K/V in L1/L2).
#define PSTR 72  // P LDS row stride in u16 (stride 36 dwords -> 2-way banks, free)
__global__ __launch_bounds__(256) void flash_attn(const u16* __restrict__ q,
                                                  const u16* __restrict__ k,
                                                  const u16* __restrict__ vt,
                                                  u16* __restrict__ o) {
  __shared__ __align__(16) u16 sP[4][32 * PSTR];
  const int tid = threadIdx.x;
  const int wave = tid >> 6, lane = tid & 63;
  const int quad = lane >> 4, l16 = lane & 15;
  const int bi = blockIdx.x;
  const int p = 31 - (bi >> 4);
  const int head = (bi & 15) * 4 + wave;
  const int b = head >> 4, hq = head & 15, kv = (head >> 2) & 3;
  const int qr0 = p * 32;
  const int n_tiles = ((qr0 + 31) >> 6) + 1;
  u16* myP = sP[wave];

  // Q fragments resident in registers: rows qr0 + i*16 + l16, k = ks*32 + quad*8
  bf16x8 aq[2][4];
  const u16* qbase = q + ((size_t)(b * 1024 + qr0) * 16 + hq) * 128;
  #pragma unroll
  for (int i = 0; i < 2; i++)
    #pragma unroll
    for (int ks = 0; ks < 4; ks++)
      aq[i][ks] = *(const bf16x8*)(qbase + (size_t)(i * 16 + l16) * 2048 + ks * 32 + quad * 8);

  const floatx4 vzero = {0.f, 0.f, 0.f, 0.f};
  floatx4 o_acc[2][8];
  float mrow[2][4], lrow[2][4];
  #pragma unroll
  for (int i = 0; i < 2; i++) {
    #pragma unroll
    for (int j = 0; j < 8; j++) o_acc[i][j] = vzero;
    #pragma unroll
    for (int r = 0; r < 4; r++) { mrow[i][r] = -1e30f; lrow[i][r] = 0.f; }
  }
  const u16* kbase = k + ((size_t)(b * 1024) * 4 + kv) * 128;
  const u16* vbase = vt + (size_t)(b * 4 + kv) * 131072;

  for (int kt = 0; kt < n_tiles; kt++) {
    const int t0 = kt * 64;
    // ---- S = Q K^T over 64 keys ----
    floatx4 s_acc[2][4];
    #pragma unroll
    for (int i = 0; i < 2; i++)
      #pragma unroll
      for (int j = 0; j < 4; j++) s_acc[i][j] = vzero;
    #pragma unroll
    for (int ks = 0; ks < 4; ks++) {
      bf16x8 bk[4];
      #pragma unroll
      for (int j = 0; j < 4; j++)
        bk[j] = *(const bf16x8*)(kbase + (size_t)(t0 + j * 16 + l16) * 512 + ks * 32 + quad * 8);
      #pragma unroll
      for (int i = 0; i < 2; i++)
        #pragma unroll
        for (int j = 0; j < 4; j++)
          s_acc[i][j] = __builtin_amdgcn_mfma_f32_16x16x32_bf16(aq[i][ks], bk[j], s_acc[i][j], 0, 0, 0);
    }
    const bool diag = (kt == n_tiles - 1);
    // ---- online softmax (rows in quads; scale pre-folded into Q) ----
    #pragma unroll
    for (int i = 0; i < 2; i++) {
      #pragma unroll
      for (int r = 0; r < 4; r++) {
        const int row_g = qr0 + i * 16 + quad * 4 + r;
        float mx = -1e30f;
        #pragma unroll
        for (int j = 0; j < 4; j++) {
          float v = s_acc[i][j][r];
          if (diag && (t0 + j * 16 + l16 > row_g)) v = -1e30f;
          s_acc[i][j][r] = v;
          mx = fmaxf(mx, v);
        }
        #pragma unroll
        for (int d = 1; d < 16; d <<= 1) mx = fmaxf(mx, __shfl_xor(mx, d));
        float mold = mrow[i][r];
        float mnew = fmaxf(mold, mx);
        float alpha = __expf(mold - mnew);
        mrow[i][r] = mnew;
        float rs = 0.f;
        #pragma unroll
        for (int j = 0; j < 4; j++) {
          float pe = __expf(s_acc[i][j][r] - mnew);
          s_acc[i][j][r] = pe;
          rs += pe;
        }
        #pragma unroll
        for (int d = 1; d < 16; d <<= 1) rs += __shfl_xor(rs, d);
        lrow[i][r] = lrow[i][r] * alpha + rs;
        #pragma unroll
        for (int j = 0; j < 8; j++) o_acc[i][j][r] *= alpha;
      }
    }
    // ---- P: C-layout -> A-layout via wave-private LDS (no barrier) ----
    #pragma unroll
    for (int i = 0; i < 2; i++)
      #pragma unroll
      for (int j = 0; j < 4; j++)
        #pragma unroll
        for (int r = 0; r < 4; r++)
          myP[(i * 16 + quad * 4 + r) * PSTR + j * 16 + l16] = f2bf(s_acc[i][j][r]);
    bf16x8 ap[2][2];
    #pragma unroll
    for (int i = 0; i < 2; i++)
      #pragma unroll
      for (int ks2 = 0; ks2 < 2; ks2++)
        ap[i][ks2] = *(const bf16x8*)&myP[(i * 16 + l16) * PSTR + ks2 * 32 + quad * 8];
    // ---- O += P V ----
    #pragma unroll
    for (int ks2 = 0; ks2 < 2; ks2++) {
      bf16x8 bv[8];
      #pragma unroll
      for (int j = 0; j < 8; j++)
        bv[j] = *(const bf16x8*)(vbase + (size_t)(j * 16 + l16) * 1024 + t0 + ks2 * 32 + quad * 8);
      #pragma unroll
      for (int i = 0; i < 2; i++)
        #pragma unroll
        for (int j = 0; j < 8; j++)
          o_acc[i][j] = __builtin_amdgcn_mfma_f32_16x16x32_bf16(ap[i][ks2], bv[j], o_acc[i][j], 0, 0, 0);
    }
  }
  // ---- epilogue: O / l -> bf16 ----
  u16* obase = o + ((size_t)(b * 1024 + qr0) * 16 + hq) * 128;
  #pragma unroll
  for (int i = 0; i < 2; i++) {
    #pragma unroll
    for (int r = 0; r < 4; r++) {
      const int row_l = i * 16 + quad * 4 + r;
      const float inv = 1.f / lrow[i][r];
      #pragma unroll
      for (int j = 0; j < 8; j++)
        obase[(size_t)row_l * 2048 + j * 16 + l16] = f2bf(o_acc[i][j][r] * inv);
    }
  }
}

extern "C" void kernel_launch(void* const* d_in, const int* in_sizes, int n_in,
                              void* d_out, int out_size, void* d_ws, size_t ws_size,
                              hipStream_t stream) {
  const float* x  = (const float*)d_in[0];
  const float* fr = (const float*)d_in[2];
  const float* wq = (const float*)d_in[4];
  const float* wk = (const float*)d_in[5];
  const float* wv = (const float*)d_in[6];
  const float* wo = (const float*)d_in[7];
  float* out = (float*)d_out;

  char* ws = (char*)d_ws;
  u16* xb  = (u16*)(ws + 0);           // 4096x2048        16.78 MB
  u16* wqb = (u16*)(ws + 16777216);    // 2048x2048         8.39 MB
  u16* wkb = (u16*)(ws + 25165824);    //  512x2048         2.10 MB
  u16* wvb = (u16*)(ws + 27262976);    //  512x2048         2.10 MB
  u16* wob = (u16*)(ws + 29360128);    // 2048x2048         8.39 MB
  u16* qb  = (u16*)(ws + 37748736);    // [B,S,16,128]     16.78 MB
  u16* kb  = (u16*)(ws + 54525952);    // [B,S,4,128]       4.19 MB
  u16* vtb = (u16*)(ws + 58720256);    // [B,4,128,S]       4.19 MB
  u16* ob  = (u16*)(ws + 62914560);    // [B,S,16,128]     16.78 MB

  cvt_all<<<18432, 256, 0, stream>>>(x, wq, wk, wv, wo, xb, wqb, wkb, wvb, wob);
  gemm_qkv<<<dim3(32, 24), 256, 0, stream>>>(xb, wqb, wkb, wvb, qb, kb, vtb);
  rope_kernel<<<16384, 256, 0, stream>>>(qb, fr, 4, 4194304, 0.08838834764831845f);
  rope_kernel<<<4096,  256, 0, stream>>>(kb, fr, 2, 1048576, 1.0f);
  flash_attn<<<512, 256, 0, stream>>>(qb, kb, vtb, ob);
  gemm_out<<<dim3(32, 16), 256, 0, stream>>>(ob, wob, out);
}